// Round 11
// baseline (126.726 us; speedup 1.0000x reference)
//
#include <hip/hip_runtime.h>

#define TS 20
#define BATCH 8192
#define LOG2E 1.4426950408889634f

typedef _Float16 half8 __attribute__((ext_vector_type(8)));
typedef float f32x4 __attribute__((ext_vector_type(4)));

__device__ __forceinline__ float fexp2(float x) {
#if __has_builtin(__builtin_amdgcn_exp2f)
    return __builtin_amdgcn_exp2f(x);
#else
    return exp2f(x);
#endif
}
// weights pre-scaled by log2e (sig) / 2log2e (tanh):
__device__ __forceinline__ float sig2(float zp)  { return __builtin_amdgcn_rcpf(1.0f + fexp2(-zp)); }
__device__ __forceinline__ float tanh2(float zp) { return 1.0f - 2.0f * __builtin_amdgcn_rcpf(1.0f + fexp2(zp)); }
// row swizzle for 16B LDS units
__device__ __forceinline__ int swz(int r) { return (r & 7) ^ (((r >> 3) & 1) << 2); }
// raw workgroup barrier (wave-uniform divergent arms with MATCHED counts)
__device__ __forceinline__ void wg_barrier() {
    asm volatile("s_waitcnt lgkmcnt(0)" ::: "memory");
    __builtin_amdgcn_s_barrier();
}

// ====== Producer-consumer fused kernel: L1 waves 0-7, L2 waves 8-15 ======
// 1024 thr (16 waves), BT=32 rows, grid=256 (1 block/CU, 4 waves/SIMD).
// KEY CHANGE vs R8/R9: explicit amdgpu_waves_per_eu(4,4) instead of
// __launch_bounds__ — hipcc pins 1024-thr blocks to VGPR=64 (R8=R9 identical,
// spill) because its default waves-per-eu heuristic isn't lowered by
// launch_bounds arg2. min 4 waves/EU -> VGPR cap 512/4 = 128, matching the
// arms' ~104-115 demand. 16 waves x 128 = 2048 = measured per-CU VGPR pool.
// Barrier counts: A-arm = 1 + 20 + 2 = 23; B-arm = 1 + 20 + 1 + 1 = 23. MATCHED.
extern "C" __global__
__attribute__((amdgpu_flat_work_group_size(1024, 1024)))
__attribute__((amdgpu_waves_per_eu(4, 4)))
void fused_lstm_pc_kernel(const float* __restrict__ x,
                          const float* __restrict__ Wih1, const float* __restrict__ Whh1,
                          const float* __restrict__ bih1, const float* __restrict__ bhh1,
                          const float* __restrict__ Wih2, const float* __restrict__ Whh2,
                          const float* __restrict__ bih2, const float* __restrict__ bhh2,
                          const float* __restrict__ gamma, const float* __restrict__ beta,
                          const float* __restrict__ W1fc, const float* __restrict__ b1fc,
                          const float* __restrict__ W2fc, const float* __restrict__ b2fc,
                          float* __restrict__ out)
{
    __shared__ __align__(16) _Float16 bf2l[4 * 4 * 2 * 64 * 8]; // Whh2 frags [cg][g][ch-4][lane] : 32 KB
    __shared__ __align__(16) _Float16 Hb[2][2][16][128];        // h1 dbuf, 16B-unit swizzled : 16 KB
    __shared__ __align__(16) _Float16 Hc[2][2][16][72];         // h2 dbuf, 144B row stride : 9 KB
    __shared__ __align__(16) _Float16 Xb[32][328];              // x fp16, 656B stride : 20.5 KB
    __shared__ float h2f[32][68];                               // final h2 for LN/FC : 8.5 KB

    const int tid  = threadIdx.x;
    const int lane = tid & 63;
    const int w    = tid >> 6;     // 0..15
    const int lrow = lane & 15;
    const int lgrp = lane >> 4;    // 0..3
    const int b0   = blockIdx.x * 32;

    // ---- common staging (no barrier yet) ----
    for (int i = tid; i < 2 * 2 * 16 * 128; i += 1024) (&Hb[0][0][0][0])[i] = (_Float16)0.0f;
    for (int i = tid; i < 2 * 2 * 16 * 72;  i += 1024) (&Hc[0][0][0][0])[i] = (_Float16)0.0f;
    for (int i = tid; i < 32 * 320; i += 1024) {
        const int r = i / 320, k = i % 320;
        Xb[r][k] = (_Float16)x[(size_t)(b0 + r) * 320 + k];
    }

    if (w < 8) {
        // ================= A role: layer 1 =================
        half8 bf[4][5];
        float bias1[4];
#pragma unroll
        for (int g = 0; g < 4; ++g) {
            const float sc = (g == 2) ? 2.0f * LOG2E : LOG2E;
            const int n = g * 128 + w * 16 + lrow;
            bias1[g] = (bih1[n] + bhh1[n]) * sc;
#pragma unroll
            for (int ch = 0; ch < 5; ++ch) {
                half8 v;
                if (ch < 4) {
                    const float4 p0 = *(const float4*)&Whh1[n * 128 + ch * 32 + lgrp * 8];
                    const float4 p1 = *(const float4*)&Whh1[n * 128 + ch * 32 + lgrp * 8 + 4];
                    v[0]=(_Float16)(p0.x*sc); v[1]=(_Float16)(p0.y*sc); v[2]=(_Float16)(p0.z*sc); v[3]=(_Float16)(p0.w*sc);
                    v[4]=(_Float16)(p1.x*sc); v[5]=(_Float16)(p1.y*sc); v[6]=(_Float16)(p1.z*sc); v[7]=(_Float16)(p1.w*sc);
                } else if (lgrp < 2) {
                    const float4 p0 = *(const float4*)&Wih1[n * 16 + lgrp * 8];
                    const float4 p1 = *(const float4*)&Wih1[n * 16 + lgrp * 8 + 4];
                    v[0]=(_Float16)(p0.x*sc); v[1]=(_Float16)(p0.y*sc); v[2]=(_Float16)(p0.z*sc); v[3]=(_Float16)(p0.w*sc);
                    v[4]=(_Float16)(p1.x*sc); v[5]=(_Float16)(p1.y*sc); v[6]=(_Float16)(p1.z*sc); v[7]=(_Float16)(p1.w*sc);
                } else {
#pragma unroll
                    for (int j = 0; j < 8; ++j) v[j] = (_Float16)0.0f;
                }
                bf[g][ch] = v;
            }
        }
        half8 kzero;
#pragma unroll
        for (int j = 0; j < 8; ++j) kzero[j] = (_Float16)0.0f;

        float c1[2][4] = {{0.f,0.f,0.f,0.f},{0.f,0.f,0.f,0.f}};
        const int hu  = (w << 1) | (lrow >> 3);
        const int hlo = lrow & 7;
        const int szr = swz(lrow);

        wg_barrier();                                   // barrier #0
        for (int t = 0; t < TS; ++t) {
            const int s = t & 1;
            f32x4 z[2][4];
#pragma unroll
            for (int tile = 0; tile < 2; ++tile)
#pragma unroll
                for (int g = 0; g < 4; ++g) z[tile][g] = (f32x4){bias1[g], bias1[g], bias1[g], bias1[g]};
#pragma unroll
            for (int ch = 0; ch < 5; ++ch) {
#pragma unroll
                for (int tile = 0; tile < 2; ++tile) {
                    half8 a;
                    if (ch < 4) a = *(const half8*)&Hb[s ^ 1][tile][lrow][(((ch << 2) | lgrp) ^ szr) * 8];
                    else        a = (lgrp < 2) ? *(const half8*)&Xb[tile * 16 + lrow][t * 16 + lgrp * 8] : kzero;
#pragma unroll
                    for (int g = 0; g < 4; ++g)
                        z[tile][g] = __builtin_amdgcn_mfma_f32_16x16x32_f16(a, bf[g][ch], z[tile][g], 0, 0, 0);
                }
            }
#pragma unroll
            for (int tile = 0; tile < 2; ++tile)
#pragma unroll
                for (int j = 0; j < 4; ++j) {
                    const float iv = sig2 (z[tile][0][j]);
                    const float fv = sig2 (z[tile][1][j]);
                    const float gv = tanh2(z[tile][2][j]);
                    const float ov = sig2 (z[tile][3][j]);
                    const float cn = fv * c1[tile][j] + iv * gv;
                    c1[tile][j] = cn;
                    const float h = ov * tanh2(2.0f * LOG2E * cn);
                    const int m = (lgrp << 2) | j;
                    Hb[s][tile][m][((hu ^ swz(m)) << 3) | hlo] = (_Float16)h;
                }
            wg_barrier();                               // barriers #1..#20 (publish h1(t))
        }
        wg_barrier();                                   // #21 (match B post-loop)
        wg_barrier();                                   // #22 (match B post-LN)
    } else {
        // ================= B role: layer 2 + LN + FC =================
        const int bw = w - 8;
        const int cg = bw & 3;       // cellgroup: cells cg*16 .. cg*16+15
        const int mt = bw >> 2;      // M-tile 0/1
        half8 w2[4][4];              // Wih2 chunks 0..3 in registers (64 VGPR)
        float bias2[4];
#pragma unroll
        for (int g = 0; g < 4; ++g) {
            const float sc = (g == 2) ? 2.0f * LOG2E : LOG2E;
            const int n = g * 64 + cg * 16 + lrow;
            bias2[g] = (bih2[n] + bhh2[n]) * sc;
#pragma unroll
            for (int ch = 0; ch < 4; ++ch) {
                const float4 p0 = *(const float4*)&Wih2[n * 128 + ch * 32 + lgrp * 8];
                const float4 p1 = *(const float4*)&Wih2[n * 128 + ch * 32 + lgrp * 8 + 4];
                half8 v;
                v[0]=(_Float16)(p0.x*sc); v[1]=(_Float16)(p0.y*sc); v[2]=(_Float16)(p0.z*sc); v[3]=(_Float16)(p0.w*sc);
                v[4]=(_Float16)(p1.x*sc); v[5]=(_Float16)(p1.y*sc); v[6]=(_Float16)(p1.z*sc); v[7]=(_Float16)(p1.w*sc);
                w2[g][ch] = v;
            }
        }
        if (bw < 4) {   // stage Whh2 fragments for cellgroup bw (chunks 4,5) -> LDS
#pragma unroll
            for (int g = 0; g < 4; ++g) {
                const float sc = (g == 2) ? 2.0f * LOG2E : LOG2E;
                const int n = g * 64 + bw * 16 + lrow;
#pragma unroll
                for (int c2i = 0; c2i < 2; ++c2i) {
                    const float4 p0 = *(const float4*)&Whh2[n * 64 + c2i * 32 + lgrp * 8];
                    const float4 p1 = *(const float4*)&Whh2[n * 64 + c2i * 32 + lgrp * 8 + 4];
                    half8 v;
                    v[0]=(_Float16)(p0.x*sc); v[1]=(_Float16)(p0.y*sc); v[2]=(_Float16)(p0.z*sc); v[3]=(_Float16)(p0.w*sc);
                    v[4]=(_Float16)(p1.x*sc); v[5]=(_Float16)(p1.y*sc); v[6]=(_Float16)(p1.z*sc); v[7]=(_Float16)(p1.w*sc);
                    ((half8*)bf2l)[((bw * 4 + g) * 2 + c2i) * 64 + lane] = v;
                }
            }
        }
        float c2[4] = {0.f, 0.f, 0.f, 0.f};
        const int cell2 = (cg << 4) | lrow;
        const int szr = swz(lrow);

        wg_barrier();                                   // barrier #0
        for (int t = 0; t < TS; ++t) {
            const int s = t & 1;
            wg_barrier();                               // barriers #1..#20 (wait h1(t))
            f32x4 z2[4];
#pragma unroll
            for (int g = 0; g < 4; ++g) z2[g] = (f32x4){bias2[g], bias2[g], bias2[g], bias2[g]};
#pragma unroll
            for (int ch = 0; ch < 4; ++ch) {
                const half8 a2 = *(const half8*)&Hb[s][mt][lrow][(((ch << 2) | lgrp) ^ szr) * 8];
#pragma unroll
                for (int g = 0; g < 4; ++g)
                    z2[g] = __builtin_amdgcn_mfma_f32_16x16x32_f16(a2, w2[g][ch], z2[g], 0, 0, 0);
            }
#pragma unroll
            for (int c2i = 0; c2i < 2; ++c2i) {
                const half8 a2 = *(const half8*)&Hc[s ^ 1][mt][lrow][c2i * 32 + lgrp * 8];
#pragma unroll
                for (int g = 0; g < 4; ++g) {
                    const half8 bfrag = ((const half8*)bf2l)[((cg * 4 + g) * 2 + c2i) * 64 + lane];
                    z2[g] = __builtin_amdgcn_mfma_f32_16x16x32_f16(a2, bfrag, z2[g], 0, 0, 0);
                }
            }
#pragma unroll
            for (int j = 0; j < 4; ++j) {
                const float iv = sig2 (z2[0][j]);
                const float fv = sig2 (z2[1][j]);
                const float gv = tanh2(z2[2][j]);
                const float ov = sig2 (z2[3][j]);
                const float cn = fv * c2[j] + iv * gv;
                c2[j] = cn;
                const float h = ov * tanh2(2.0f * LOG2E * cn);
                const int m = (lgrp << 2) | j;
                Hc[s][mt][m][cell2] = (_Float16)h;
                if (t == TS - 1) h2f[(mt << 4) | m][cell2] = h;
            }
        }
        wg_barrier();                                   // #21 (h2f visible across B waves)
        {   // LN: 512 B-threads, one (row, quad) each
            const int bt = tid - 512;
            const int m = bt >> 4, q = bt & 15;
            const float v0 = h2f[m][q * 4 + 0];
            const float v1 = h2f[m][q * 4 + 1];
            const float v2 = h2f[m][q * 4 + 2];
            const float v3 = h2f[m][q * 4 + 3];
            float ssum = v0 + v1 + v2 + v3;
            ssum += __shfl_xor(ssum, 1); ssum += __shfl_xor(ssum, 2);
            ssum += __shfl_xor(ssum, 4); ssum += __shfl_xor(ssum, 8);
            const float mean = ssum * (1.0f / 64.0f);
            const float d0 = v0 - mean, d1 = v1 - mean, d2 = v2 - mean, d3 = v3 - mean;
            float vs = d0 * d0 + d1 * d1 + d2 * d2 + d3 * d3;
            vs += __shfl_xor(vs, 1); vs += __shfl_xor(vs, 2);
            vs += __shfl_xor(vs, 4); vs += __shfl_xor(vs, 8);
            const float rstd = rsqrtf(vs * (1.0f / 64.0f) + 1e-5f);
            const int i0 = q * 4;
            h2f[m][i0 + 0] = d0 * rstd * gamma[i0 + 0] + beta[i0 + 0];
            h2f[m][i0 + 1] = d1 * rstd * gamma[i0 + 1] + beta[i0 + 1];
            h2f[m][i0 + 2] = d2 * rstd * gamma[i0 + 2] + beta[i0 + 2];
            h2f[m][i0 + 3] = d3 * rstd * gamma[i0 + 3] + beta[i0 + 3];
        }
        wg_barrier();                                   // #22
        {   // FC1(relu)+FC2: o = fc unit, 16 row-groups x 2
            const int bt = tid - 512;
            const int o = bt & 31;
            const int mgrp = bt >> 5;    // 0..15
#pragma unroll
            for (int rr = 0; rr < 2; ++rr) {
                const int m = mgrp + rr * 16;
                float acc = b1fc[o];
#pragma unroll 8
                for (int k = 0; k < 64; ++k) acc += h2f[m][k] * W1fc[o * 64 + k];
                const float hv = fmaxf(acc, 0.0f);
                float p = hv * W2fc[o];
                p += __shfl_xor(p, 1); p += __shfl_xor(p, 2);
                p += __shfl_xor(p, 4); p += __shfl_xor(p, 8); p += __shfl_xor(p, 16);
                if (o == 0) out[b0 + m] = p + b2fc[0];
            }
        }
    }
}

extern "C" void kernel_launch(void* const* d_in, const int* in_sizes, int n_in,
                              void* d_out, int out_size, void* d_ws, size_t ws_size,
                              hipStream_t stream) {
    (void)in_sizes; (void)n_in; (void)d_ws; (void)ws_size; (void)out_size;
    const float* x_p    = (const float*)d_in[0];
    const float* Wih1_p = (const float*)d_in[1];
    const float* Whh1_p = (const float*)d_in[2];
    const float* bih1_p = (const float*)d_in[3];
    const float* bhh1_p = (const float*)d_in[4];
    const float* Wih2_p = (const float*)d_in[5];
    const float* Whh2_p = (const float*)d_in[6];
    const float* bih2_p = (const float*)d_in[7];
    const float* bhh2_p = (const float*)d_in[8];
    const float* gamma_p = (const float*)d_in[9];
    const float* beta_p  = (const float*)d_in[10];
    const float* W1_p   = (const float*)d_in[11];
    const float* b1_p   = (const float*)d_in[12];
    const float* W2_p   = (const float*)d_in[13];
    const float* b2_p   = (const float*)d_in[14];
    float* out_p = (float*)d_out;

    fused_lstm_pc_kernel<<<dim3(BATCH / 32), dim3(1024), 0, stream>>>(
        x_p, Wih1_p, Whh1_p, bih1_p, bhh1_p,
        Wih2_p, Whh2_p, bih2_p, bhh2_p,
        gamma_p, beta_p, W1_p, b1_p, W2_p, b2_p, out_p);
}

// Round 12
// 109.972 us; speedup vs baseline: 1.1524x; 1.1524x over previous
//
#include <hip/hip_runtime.h>

#define TS 20
#define BATCH 8192
#define LOG2E 1.4426950408889634f

typedef _Float16 half8 __attribute__((ext_vector_type(8)));
typedef float f32x4 __attribute__((ext_vector_type(4)));

__device__ __forceinline__ float fexp2(float x) {
#if __has_builtin(__builtin_amdgcn_exp2f)
    return __builtin_amdgcn_exp2f(x);
#else
    return exp2f(x);
#endif
}
// weights pre-scaled by log2e (sig) / 2log2e (tanh):
__device__ __forceinline__ float sig2(float zp)  { return __builtin_amdgcn_rcpf(1.0f + fexp2(-zp)); }
__device__ __forceinline__ float tanh2(float zp) { return 1.0f - 2.0f * __builtin_amdgcn_rcpf(1.0f + fexp2(zp)); }
// row swizzle for 16B LDS units
__device__ __forceinline__ int swz(int r) { return (r & 7) ^ (((r >> 3) & 1) << 2); }

// ====== Fat-wave fused kernel: 256 thr (4 waves), BT=32, grid=256 ======
// Allocation ledger across R1-R11: default VGPR cap = 1024/nWaves (hipcc
// assumes 2 blocks/CU): 512thr->128 (R10 spilled at 220 demand), 1024thr->64
// always. 256thr (4 waves) -> cap 256: first shape that FITS a fat register
// set. Each wave: 2 L1 cellgroups in VGPR (160) + 1 L2 cellgroup streamed
// from LDS. L2(t-1) computed in the same barrier window as L1(t) (lagged
// pipeline): two independent instruction streams per wave -> ILP hides all
// latency with 1 wave/SIMD; all 4 matrix pipes driven at the ~2483 cyc/step
// CU floor. ONE barrier/step. No launch_bounds arg2 (would lower the cap).
extern "C" __global__ __launch_bounds__(256)
void fused_lstm_fat_kernel(const float* __restrict__ x,
                           const float* __restrict__ Wih1, const float* __restrict__ Whh1,
                           const float* __restrict__ bih1, const float* __restrict__ bhh1,
                           const float* __restrict__ Wih2, const float* __restrict__ Whh2,
                           const float* __restrict__ bih2, const float* __restrict__ bhh2,
                           const float* __restrict__ gamma, const float* __restrict__ beta,
                           const float* __restrict__ W1fc, const float* __restrict__ b1fc,
                           const float* __restrict__ W2fc, const float* __restrict__ b2fc,
                           float* __restrict__ out)
{
    __shared__ __align__(16) _Float16 bf2l[4 * 4 * 6 * 64 * 8]; // L2 W frags [cg][g][ch][lane] : 96 KB
    __shared__ __align__(16) _Float16 Hb[2][2][16][128];        // h1 dbuf, 16B-unit swizzled : 16 KB
    __shared__ __align__(16) _Float16 Hc[2][2][16][72];         // h2 dbuf, 144B row stride : 9 KB
    __shared__ __align__(16) _Float16 Xb[32][328];              // x fp16, 656B stride : 20.5 KB
    __shared__ float h2f[32][68];                               // final h2 for LN/FC : 8.5 KB

    const int tid  = threadIdx.x;
    const int lane = tid & 63;
    const int w    = tid >> 6;     // 0..3
    const int lrow = lane & 15;
    const int lgrp = lane >> 4;    // 0..3
    const int b0   = blockIdx.x * 32;

    // ---- L1 weights: cellgroups w and w+4 (160 VGPR), pre-scaled ----
    half8 bf1[2][4][5];
    float bias1[2][4];
#pragma unroll
    for (int cgi = 0; cgi < 2; ++cgi) {
        const int cg = w + cgi * 4;
#pragma unroll
        for (int g = 0; g < 4; ++g) {
            const float sc = (g == 2) ? 2.0f * LOG2E : LOG2E;
            const int n = g * 128 + cg * 16 + lrow;
            bias1[cgi][g] = (bih1[n] + bhh1[n]) * sc;
#pragma unroll
            for (int ch = 0; ch < 5; ++ch) {
                half8 v;
                if (ch < 4) {
                    const float4 p0 = *(const float4*)&Whh1[n * 128 + ch * 32 + lgrp * 8];
                    const float4 p1 = *(const float4*)&Whh1[n * 128 + ch * 32 + lgrp * 8 + 4];
                    v[0]=(_Float16)(p0.x*sc); v[1]=(_Float16)(p0.y*sc); v[2]=(_Float16)(p0.z*sc); v[3]=(_Float16)(p0.w*sc);
                    v[4]=(_Float16)(p1.x*sc); v[5]=(_Float16)(p1.y*sc); v[6]=(_Float16)(p1.z*sc); v[7]=(_Float16)(p1.w*sc);
                } else if (lgrp < 2) {
                    const float4 p0 = *(const float4*)&Wih1[n * 16 + lgrp * 8];
                    const float4 p1 = *(const float4*)&Wih1[n * 16 + lgrp * 8 + 4];
                    v[0]=(_Float16)(p0.x*sc); v[1]=(_Float16)(p0.y*sc); v[2]=(_Float16)(p0.z*sc); v[3]=(_Float16)(p0.w*sc);
                    v[4]=(_Float16)(p1.x*sc); v[5]=(_Float16)(p1.y*sc); v[6]=(_Float16)(p1.z*sc); v[7]=(_Float16)(p1.w*sc);
                } else {
#pragma unroll
                    for (int j = 0; j < 8; ++j) v[j] = (_Float16)0.0f;
                }
                bf1[cgi][g][ch] = v;
            }
        }
    }
    // ---- L2 bias + stage bf2l for cellgroup w ----
    float bias2[4];
#pragma unroll
    for (int g = 0; g < 4; ++g) {
        const float sc = (g == 2) ? 2.0f * LOG2E : LOG2E;
        const int n = g * 64 + w * 16 + lrow;
        bias2[g] = (bih2[n] + bhh2[n]) * sc;
#pragma unroll
        for (int ch = 0; ch < 6; ++ch) {
            const float4 p0 = (ch < 4) ? *(const float4*)&Wih2[n * 128 + ch * 32 + lgrp * 8]
                                       : *(const float4*)&Whh2[n * 64 + (ch - 4) * 32 + lgrp * 8];
            const float4 p1 = (ch < 4) ? *(const float4*)&Wih2[n * 128 + ch * 32 + lgrp * 8 + 4]
                                       : *(const float4*)&Whh2[n * 64 + (ch - 4) * 32 + lgrp * 8 + 4];
            half8 v;
            v[0]=(_Float16)(p0.x*sc); v[1]=(_Float16)(p0.y*sc); v[2]=(_Float16)(p0.z*sc); v[3]=(_Float16)(p0.w*sc);
            v[4]=(_Float16)(p1.x*sc); v[5]=(_Float16)(p1.y*sc); v[6]=(_Float16)(p1.z*sc); v[7]=(_Float16)(p1.w*sc);
            ((half8*)bf2l)[((w * 4 + g) * 6 + ch) * 64 + lane] = v;
        }
    }

    // ---- zero h-state, stage x as fp16 ----
    for (int i = tid; i < 2 * 2 * 16 * 128; i += 256) (&Hb[0][0][0][0])[i] = (_Float16)0.0f;
    for (int i = tid; i < 2 * 2 * 16 * 72;  i += 256) (&Hc[0][0][0][0])[i] = (_Float16)0.0f;
    for (int i = tid; i < 32 * 320; i += 256) {
        const int r = i / 320, k = i % 320;
        Xb[r][k] = (_Float16)x[(size_t)(b0 + r) * 320 + k];
    }
    half8 kzero;
#pragma unroll
    for (int j = 0; j < 8; ++j) kzero[j] = (_Float16)0.0f;

    float c1[2][2][4];   // [tile][cgi][j]
    float c2[2][4];      // [tile][j]
#pragma unroll
    for (int a = 0; a < 2; ++a)
#pragma unroll
        for (int b = 0; b < 2; ++b)
#pragma unroll
            for (int j = 0; j < 4; ++j) { c1[a][b][j] = 0.f; if (b == 0) c2[a][j] = 0.f; }

    const int szr   = swz(lrow);
    const int hlo   = lrow & 7;
    const int cell2 = (w << 4) | lrow;

    __syncthreads();

    for (int t = 0; t < TS; ++t) {
        const int s = t & 1;
        // ======== L2(t-1), lagged one step (reads stable Hb[s^1]) ========
        if (t > 0) {
            const int sp = s ^ 1;
#pragma unroll
            for (int tile = 0; tile < 2; ++tile) {
                f32x4 z2[4];
#pragma unroll
                for (int g = 0; g < 4; ++g) z2[g] = (f32x4){bias2[g], bias2[g], bias2[g], bias2[g]};
#pragma unroll
                for (int ch = 0; ch < 6; ++ch) {
                    const half8 a2 = (ch < 4)
                        ? *(const half8*)&Hb[sp][tile][lrow][(((ch << 2) | lgrp) ^ szr) * 8]
                        : *(const half8*)&Hc[sp ^ 1][tile][lrow][(ch - 4) * 32 + lgrp * 8];
#pragma unroll
                    for (int g = 0; g < 4; ++g) {
                        const half8 wf = ((const half8*)bf2l)[((w * 4 + g) * 6 + ch) * 64 + lane];
                        z2[g] = __builtin_amdgcn_mfma_f32_16x16x32_f16(a2, wf, z2[g], 0, 0, 0);
                    }
                }
#pragma unroll
                for (int j = 0; j < 4; ++j) {
                    const float iv = sig2 (z2[0][j]);
                    const float fv = sig2 (z2[1][j]);
                    const float gv = tanh2(z2[2][j]);
                    const float ov = sig2 (z2[3][j]);
                    const float cn = fv * c2[tile][j] + iv * gv;
                    c2[tile][j] = cn;
                    const float h = ov * tanh2(2.0f * LOG2E * cn);
                    const int m = (lgrp << 2) | j;
                    Hc[sp][tile][m][cell2] = (_Float16)h;
                }
            }
        }
        // ======== L1(t): both tiles x both cellgroups ========
#pragma unroll
        for (int tile = 0; tile < 2; ++tile) {
#pragma unroll
            for (int cgi = 0; cgi < 2; ++cgi) {
                f32x4 z[4];
#pragma unroll
                for (int g = 0; g < 4; ++g) z[g] = (f32x4){bias1[cgi][g], bias1[cgi][g], bias1[cgi][g], bias1[cgi][g]};
#pragma unroll
                for (int ch = 0; ch < 5; ++ch) {
                    half8 a;
                    if (ch < 4) a = *(const half8*)&Hb[s ^ 1][tile][lrow][(((ch << 2) | lgrp) ^ szr) * 8];
                    else        a = (lgrp < 2) ? *(const half8*)&Xb[tile * 16 + lrow][t * 16 + lgrp * 8] : kzero;
#pragma unroll
                    for (int g = 0; g < 4; ++g)
                        z[g] = __builtin_amdgcn_mfma_f32_16x16x32_f16(a, bf1[cgi][g][ch], z[g], 0, 0, 0);
                }
                const int cg = w + cgi * 4;
                const int hu = (cg << 1) | (lrow >> 3);
#pragma unroll
                for (int j = 0; j < 4; ++j) {
                    const float iv = sig2 (z[0][j]);
                    const float fv = sig2 (z[1][j]);
                    const float gv = tanh2(z[2][j]);
                    const float ov = sig2 (z[3][j]);
                    const float cn = fv * c1[tile][cgi][j] + iv * gv;
                    c1[tile][cgi][j] = cn;
                    const float h = ov * tanh2(2.0f * LOG2E * cn);
                    const int m = (lgrp << 2) | j;
                    Hb[s][tile][m][((hu ^ swz(m)) << 3) | hlo] = (_Float16)h;
                }
            }
        }
        __syncthreads();
    }
    // ======== final L2(TS-1) ========
    {
        const int sp = (TS - 1) & 1;
#pragma unroll
        for (int tile = 0; tile < 2; ++tile) {
            f32x4 z2[4];
#pragma unroll
            for (int g = 0; g < 4; ++g) z2[g] = (f32x4){bias2[g], bias2[g], bias2[g], bias2[g]};
#pragma unroll
            for (int ch = 0; ch < 6; ++ch) {
                const half8 a2 = (ch < 4)
                    ? *(const half8*)&Hb[sp][tile][lrow][(((ch << 2) | lgrp) ^ szr) * 8]
                    : *(const half8*)&Hc[sp ^ 1][tile][lrow][(ch - 4) * 32 + lgrp * 8];
#pragma unroll
                for (int g = 0; g < 4; ++g) {
                    const half8 wf = ((const half8*)bf2l)[((w * 4 + g) * 6 + ch) * 64 + lane];
                    z2[g] = __builtin_amdgcn_mfma_f32_16x16x32_f16(a2, wf, z2[g], 0, 0, 0);
                }
            }
#pragma unroll
            for (int j = 0; j < 4; ++j) {
                const float iv = sig2 (z2[0][j]);
                const float fv = sig2 (z2[1][j]);
                const float gv = tanh2(z2[2][j]);
                const float ov = sig2 (z2[3][j]);
                const float cn = fv * c2[tile][j] + iv * gv;
                c2[tile][j] = cn;
                const float h = ov * tanh2(2.0f * LOG2E * cn);
                const int m = (lgrp << 2) | j;
                h2f[(tile << 4) | m][cell2] = h;
            }
        }
    }
    __syncthreads();

    // ---- epilogue: LayerNorm (8 thr/row) + FC1(relu) + FC2 ----
    {
        const int m = tid >> 3, q = tid & 7;   // 32 rows x 8 threads
        float v[8];
#pragma unroll
        for (int i = 0; i < 8; ++i) v[i] = h2f[m][q * 8 + i];
        float ssum = 0.f;
#pragma unroll
        for (int i = 0; i < 8; ++i) ssum += v[i];
        ssum += __shfl_xor(ssum, 1); ssum += __shfl_xor(ssum, 2); ssum += __shfl_xor(ssum, 4);
        const float mean = ssum * (1.0f / 64.0f);
        float vs = 0.f;
#pragma unroll
        for (int i = 0; i < 8; ++i) { const float d = v[i] - mean; vs += d * d; }
        vs += __shfl_xor(vs, 1); vs += __shfl_xor(vs, 2); vs += __shfl_xor(vs, 4);
        const float rstd = rsqrtf(vs * (1.0f / 64.0f) + 1e-5f);
#pragma unroll
        for (int i = 0; i < 8; ++i) {
            const int k = q * 8 + i;
            h2f[m][k] = (v[i] - mean) * rstd * gamma[k] + beta[k];
        }
    }
    __syncthreads();
    {
        const int o  = tid & 31;
        const int mg = tid >> 5;   // 0..7
#pragma unroll
        for (int rr = 0; rr < 4; ++rr) {
            const int m = mg + rr * 8;
            float acc = b1fc[o];
#pragma unroll 8
            for (int k = 0; k < 64; ++k) acc += h2f[m][k] * W1fc[o * 64 + k];
            const float hv = fmaxf(acc, 0.0f);
            float p = hv * W2fc[o];
            p += __shfl_xor(p, 1); p += __shfl_xor(p, 2);
            p += __shfl_xor(p, 4); p += __shfl_xor(p, 8); p += __shfl_xor(p, 16);
            if (o == 0) out[b0 + m] = p + b2fc[0];
        }
    }
}

extern "C" void kernel_launch(void* const* d_in, const int* in_sizes, int n_in,
                              void* d_out, int out_size, void* d_ws, size_t ws_size,
                              hipStream_t stream) {
    (void)in_sizes; (void)n_in; (void)d_ws; (void)ws_size; (void)out_size;
    const float* x_p    = (const float*)d_in[0];
    const float* Wih1_p = (const float*)d_in[1];
    const float* Whh1_p = (const float*)d_in[2];
    const float* bih1_p = (const float*)d_in[3];
    const float* bhh1_p = (const float*)d_in[4];
    const float* Wih2_p = (const float*)d_in[5];
    const float* Whh2_p = (const float*)d_in[6];
    const float* bih2_p = (const float*)d_in[7];
    const float* bhh2_p = (const float*)d_in[8];
    const float* gamma_p = (const float*)d_in[9];
    const float* beta_p  = (const float*)d_in[10];
    const float* W1_p   = (const float*)d_in[11];
    const float* b1_p   = (const float*)d_in[12];
    const float* W2_p   = (const float*)d_in[13];
    const float* b2_p   = (const float*)d_in[14];
    float* out_p = (float*)d_out;

    fused_lstm_fat_kernel<<<dim3(BATCH / 32), dim3(256), 0, stream>>>(
        x_p, Wih1_p, Whh1_p, bih1_p, bhh1_p,
        Wih2_p, Whh2_p, bih2_p, bhh2_p,
        gamma_p, beta_p, W1_p, b1_p, W2_p, b2_p, out_p);
}

// Round 13
// 76.881 us; speedup vs baseline: 1.6483x; 1.4304x over previous
//
#include <hip/hip_runtime.h>

#define TS 20
#define BATCH 8192
#define LOG2E 1.4426950408889634f

typedef _Float16 half8 __attribute__((ext_vector_type(8)));
typedef float f32x4 __attribute__((ext_vector_type(4)));

__device__ __forceinline__ float fexp2(float x) {
#if __has_builtin(__builtin_amdgcn_exp2f)
    return __builtin_amdgcn_exp2f(x);
#else
    return exp2f(x);
#endif
}
// weights pre-scaled by log2e (sig) / 2log2e (tanh):
__device__ __forceinline__ float sig2(float zp)  { return __builtin_amdgcn_rcpf(1.0f + fexp2(-zp)); }
__device__ __forceinline__ float tanh2(float zp) { return 1.0f - 2.0f * __builtin_amdgcn_rcpf(1.0f + fexp2(zp)); }
// row swizzle for 16B LDS units
__device__ __forceinline__ int swz(int r) { return (r & 7) ^ (((r >> 3) & 1) << 2); }

// ============ Fused LSTM1+LSTM2+LN+FC, ROTATED loop ============
// R7 structure (best measured: 512thr, 8 waves, BT=32, grid=256, 1 barrier/step)
// with the loop rotated so each barrier window contains B(t);A(t+1) as
// STRAIGHT-LINE code: the two independent streams (B: 24 MFMA+40 trans,
// A: 40 MFMA+80 trans) can now be interleaved by the scheduler instead of
// being separated by the loop backedge. Same barrier count, same ordering.
extern "C" __global__ __launch_bounds__(512, 1)
void fused_lstm_rot_kernel(const float* __restrict__ x,
                           const float* __restrict__ Wih1, const float* __restrict__ Whh1,
                           const float* __restrict__ bih1, const float* __restrict__ bhh1,
                           const float* __restrict__ Wih2, const float* __restrict__ Whh2,
                           const float* __restrict__ bih2, const float* __restrict__ bhh2,
                           const float* __restrict__ gamma, const float* __restrict__ beta,
                           const float* __restrict__ W1fc, const float* __restrict__ b1fc,
                           const float* __restrict__ W2fc, const float* __restrict__ b2fc,
                           float* __restrict__ out)
{
    __shared__ __align__(16) _Float16 bf2l[4 * 4 * 6 * 64 * 8];  // L2 weight frags : 96 KB
    __shared__ __align__(16) _Float16 Hb[2][2][16][128];         // h1 dbuf, swizzled : 16 KB
    __shared__ __align__(16) _Float16 Hc[2][2][16][72];          // h2 dbuf : 9 KB
    __shared__ __align__(16) _Float16 Xb[32][328];               // x fp16 : 20.5 KB
    __shared__ float h2f[32][68];                                // final h2 : 8.5 KB

    const int tid  = threadIdx.x;
    const int lane = tid & 63;
    const int w    = tid >> 6;     // 0..7
    const int lrow = lane & 15;
    const int lgrp = lane >> 4;    // 0..3
    const int b0   = blockIdx.x * 32;

    // ---- L1 weights in VGPRs (80), pre-scaled ----
    half8 bf[4][5];
    float bias1[4];
#pragma unroll
    for (int g = 0; g < 4; ++g) {
        const float sc = (g == 2) ? 2.0f * LOG2E : LOG2E;
        const int n = g * 128 + w * 16 + lrow;
        bias1[g] = (bih1[n] + bhh1[n]) * sc;
#pragma unroll
        for (int ch = 0; ch < 5; ++ch) {
            half8 v;
            if (ch < 4) {
                const float4 p0 = *(const float4*)&Whh1[n * 128 + ch * 32 + lgrp * 8];
                const float4 p1 = *(const float4*)&Whh1[n * 128 + ch * 32 + lgrp * 8 + 4];
                v[0]=(_Float16)(p0.x*sc); v[1]=(_Float16)(p0.y*sc); v[2]=(_Float16)(p0.z*sc); v[3]=(_Float16)(p0.w*sc);
                v[4]=(_Float16)(p1.x*sc); v[5]=(_Float16)(p1.y*sc); v[6]=(_Float16)(p1.z*sc); v[7]=(_Float16)(p1.w*sc);
            } else if (lgrp < 2) {
                const float4 p0 = *(const float4*)&Wih1[n * 16 + lgrp * 8];
                const float4 p1 = *(const float4*)&Wih1[n * 16 + lgrp * 8 + 4];
                v[0]=(_Float16)(p0.x*sc); v[1]=(_Float16)(p0.y*sc); v[2]=(_Float16)(p0.z*sc); v[3]=(_Float16)(p0.w*sc);
                v[4]=(_Float16)(p1.x*sc); v[5]=(_Float16)(p1.y*sc); v[6]=(_Float16)(p1.z*sc); v[7]=(_Float16)(p1.w*sc);
            } else {
#pragma unroll
                for (int j = 0; j < 8; ++j) v[j] = (_Float16)0.0f;
            }
            bf[g][ch] = v;
        }
    }

    // ---- L2 bias + stage bf2l (waves 0..3 stage cellgroup w) ----
    const int cg = w & 3;
    const int mt = w >> 2;
    float bias2[4];
#pragma unroll
    for (int g = 0; g < 4; ++g) {
        const float sc = (g == 2) ? 2.0f * LOG2E : LOG2E;
        const int n = g * 64 + cg * 16 + lrow;
        bias2[g] = (bih2[n] + bhh2[n]) * sc;
    }
    if (w < 4) {
#pragma unroll
        for (int g = 0; g < 4; ++g) {
            const float sc = (g == 2) ? 2.0f * LOG2E : LOG2E;
            const int n = g * 64 + w * 16 + lrow;
#pragma unroll
            for (int ch = 0; ch < 6; ++ch) {
                const float4 p0 = (ch < 4) ? *(const float4*)&Wih2[n * 128 + ch * 32 + lgrp * 8]
                                           : *(const float4*)&Whh2[n * 64 + (ch - 4) * 32 + lgrp * 8];
                const float4 p1 = (ch < 4) ? *(const float4*)&Wih2[n * 128 + ch * 32 + lgrp * 8 + 4]
                                           : *(const float4*)&Whh2[n * 64 + (ch - 4) * 32 + lgrp * 8 + 4];
                half8 v;
                v[0]=(_Float16)(p0.x*sc); v[1]=(_Float16)(p0.y*sc); v[2]=(_Float16)(p0.z*sc); v[3]=(_Float16)(p0.w*sc);
                v[4]=(_Float16)(p1.x*sc); v[5]=(_Float16)(p1.y*sc); v[6]=(_Float16)(p1.z*sc); v[7]=(_Float16)(p1.w*sc);
                ((half8*)bf2l)[((w * 4 + g) * 6 + ch) * 64 + lane] = v;
            }
        }
    }

    // ---- zero h-state, stage x as fp16 ----
    for (int i = tid; i < 2 * 2 * 16 * 128; i += 512) (&Hb[0][0][0][0])[i] = (_Float16)0.0f;
    for (int i = tid; i < 2 * 2 * 16 * 72;  i += 512) (&Hc[0][0][0][0])[i] = (_Float16)0.0f;
    for (int i = tid; i < 32 * 320; i += 512) {
        const int r = i / 320, k = i % 320;
        Xb[r][k] = (_Float16)x[(size_t)(b0 + r) * 320 + k];
    }
    half8 kzero;
#pragma unroll
    for (int j = 0; j < 8; ++j) kzero[j] = (_Float16)0.0f;

    float c1[2][4] = {{0.f,0.f,0.f,0.f},{0.f,0.f,0.f,0.f}};
    float c2[4] = {0.f, 0.f, 0.f, 0.f};
    const int hu  = (w << 1) | (lrow >> 3);
    const int hlo = lrow & 7;
    const int szr = swz(lrow);
    const int cell2 = (cg << 4) | lrow;

    // phase A(tt): h1(tt) from Hb[(tt&1)^1] + Xb[:,tt*16..] -> Hb[tt&1]
    auto phaseA = [&](int tt) {
        const int sA = tt & 1;
#pragma unroll
        for (int tile = 0; tile < 2; ++tile) {
            half8 a[5];
#pragma unroll
            for (int ch = 0; ch < 4; ++ch)
                a[ch] = *(const half8*)&Hb[sA ^ 1][tile][lrow][(((ch << 2) | lgrp) ^ szr) * 8];
            a[4] = (lgrp < 2) ? *(const half8*)&Xb[tile * 16 + lrow][tt * 16 + lgrp * 8] : kzero;
            f32x4 z[4];
#pragma unroll
            for (int g = 0; g < 4; ++g) z[g] = (f32x4){bias1[g], bias1[g], bias1[g], bias1[g]};
#pragma unroll
            for (int ch = 0; ch < 5; ++ch)
#pragma unroll
                for (int g = 0; g < 4; ++g)
                    z[g] = __builtin_amdgcn_mfma_f32_16x16x32_f16(a[ch], bf[g][ch], z[g], 0, 0, 0);
#pragma unroll
            for (int j = 0; j < 4; ++j) {
                const float iv = sig2 (z[0][j]);
                const float fv = sig2 (z[1][j]);
                const float gv = tanh2(z[2][j]);
                const float ov = sig2 (z[3][j]);
                const float cn = fv * c1[tile][j] + iv * gv;
                c1[tile][j] = cn;
                const float h = ov * tanh2(2.0f * LOG2E * cn);
                const int m = (lgrp << 2) | j;
                Hb[sA][tile][m][((hu ^ swz(m)) << 3) | hlo] = (_Float16)h;
            }
        }
    };
    // phase B(tt): h2(tt) from Hb[tt&1] + Hc[(tt&1)^1] -> Hc[tt&1] (+h2f if last)
    auto phaseB = [&](int tt, bool last) {
        const int sB = tt & 1;
        f32x4 z2[4];
#pragma unroll
        for (int g = 0; g < 4; ++g) z2[g] = (f32x4){bias2[g], bias2[g], bias2[g], bias2[g]};
#pragma unroll
        for (int ch = 0; ch < 6; ++ch) {
            const half8 a2 = (ch < 4)
                ? *(const half8*)&Hb[sB][mt][lrow][(((ch << 2) | lgrp) ^ szr) * 8]
                : *(const half8*)&Hc[sB ^ 1][mt][lrow][(ch - 4) * 32 + lgrp * 8];
#pragma unroll
            for (int g = 0; g < 4; ++g) {
                const half8 wf = ((const half8*)bf2l)[((cg * 4 + g) * 6 + ch) * 64 + lane];
                z2[g] = __builtin_amdgcn_mfma_f32_16x16x32_f16(a2, wf, z2[g], 0, 0, 0);
            }
        }
#pragma unroll
        for (int j = 0; j < 4; ++j) {
            const float iv = sig2 (z2[0][j]);
            const float fv = sig2 (z2[1][j]);
            const float gv = tanh2(z2[2][j]);
            const float ov = sig2 (z2[3][j]);
            const float cn = fv * c2[j] + iv * gv;
            c2[j] = cn;
            const float h = ov * tanh2(2.0f * LOG2E * cn);
            const int m = (lgrp << 2) | j;
            Hc[sB][mt][m][cell2] = (_Float16)h;
            if (last) h2f[(mt << 4) | m][cell2] = h;
        }
    };

    __syncthreads();          // staging visible
    phaseA(0);                // h1(0)
    __syncthreads();          // publish h1(0)

#pragma unroll 2
    for (int t = 0; t < TS - 1; ++t) {
        // ROTATED WINDOW: B(t) and A(t+1) are independent straight-line streams
        phaseB(t, false);
        phaseA(t + 1);
        __syncthreads();
    }
    phaseB(TS - 1, true);
    __syncthreads();

    // ---- epilogue: LayerNorm + FC1(relu) + FC2 ----
    {
        const int m = tid >> 4, q = tid & 15;
        const float v0 = h2f[m][q * 4 + 0];
        const float v1 = h2f[m][q * 4 + 1];
        const float v2 = h2f[m][q * 4 + 2];
        const float v3 = h2f[m][q * 4 + 3];
        float ssum = v0 + v1 + v2 + v3;
        ssum += __shfl_xor(ssum, 1); ssum += __shfl_xor(ssum, 2);
        ssum += __shfl_xor(ssum, 4); ssum += __shfl_xor(ssum, 8);
        const float mean = ssum * (1.0f / 64.0f);
        const float d0 = v0 - mean, d1 = v1 - mean, d2 = v2 - mean, d3 = v3 - mean;
        float vs = d0 * d0 + d1 * d1 + d2 * d2 + d3 * d3;
        vs += __shfl_xor(vs, 1); vs += __shfl_xor(vs, 2);
        vs += __shfl_xor(vs, 4); vs += __shfl_xor(vs, 8);
        const float rstd = rsqrtf(vs * (1.0f / 64.0f) + 1e-5f);
        const int i0 = q * 4;
        h2f[m][i0 + 0] = d0 * rstd * gamma[i0 + 0] + beta[i0 + 0];
        h2f[m][i0 + 1] = d1 * rstd * gamma[i0 + 1] + beta[i0 + 1];
        h2f[m][i0 + 2] = d2 * rstd * gamma[i0 + 2] + beta[i0 + 2];
        h2f[m][i0 + 3] = d3 * rstd * gamma[i0 + 3] + beta[i0 + 3];
    }
    __syncthreads();
    {
        const int o = tid & 31;
        const int mgrp = tid >> 5;    // 0..15
#pragma unroll
        for (int rr = 0; rr < 2; ++rr) {
            const int m = mgrp + rr * 16;
            float acc = b1fc[o];
#pragma unroll 8
            for (int k = 0; k < 64; ++k) acc += h2f[m][k] * W1fc[o * 64 + k];
            const float hv = fmaxf(acc, 0.0f);
            float p = hv * W2fc[o];
            p += __shfl_xor(p, 1); p += __shfl_xor(p, 2);
            p += __shfl_xor(p, 4); p += __shfl_xor(p, 8); p += __shfl_xor(p, 16);
            if (o == 0) out[b0 + m] = p + b2fc[0];
        }
    }
}

extern "C" void kernel_launch(void* const* d_in, const int* in_sizes, int n_in,
                              void* d_out, int out_size, void* d_ws, size_t ws_size,
                              hipStream_t stream) {
    (void)in_sizes; (void)n_in; (void)d_ws; (void)ws_size; (void)out_size;
    const float* x_p    = (const float*)d_in[0];
    const float* Wih1_p = (const float*)d_in[1];
    const float* Whh1_p = (const float*)d_in[2];
    const float* bih1_p = (const float*)d_in[3];
    const float* bhh1_p = (const float*)d_in[4];
    const float* Wih2_p = (const float*)d_in[5];
    const float* Whh2_p = (const float*)d_in[6];
    const float* bih2_p = (const float*)d_in[7];
    const float* bhh2_p = (const float*)d_in[8];
    const float* gamma_p = (const float*)d_in[9];
    const float* beta_p  = (const float*)d_in[10];
    const float* W1_p   = (const float*)d_in[11];
    const float* b1_p   = (const float*)d_in[12];
    const float* W2_p   = (const float*)d_in[13];
    const float* b2_p   = (const float*)d_in[14];
    float* out_p = (float*)d_out;

    fused_lstm_rot_kernel<<<dim3(BATCH / 32), dim3(512), 0, stream>>>(
        x_p, Wih1_p, Whh1_p, bih1_p, bhh1_p,
        Wih2_p, Whh2_p, bih2_p, bhh2_p,
        gamma_p, beta_p, W1_p, b1_p, W2_p, b2_p, out_p);
}